// Round 2
// baseline (252.708 us; speedup 1.0000x reference)
//
#include <hip/hip_runtime.h>

#define NEG_INF (-9999999.0f)

typedef __attribute__((ext_vector_type(8))) short bf16x8;
typedef __attribute__((ext_vector_type(4))) float f32x4;
typedef unsigned short us;
typedef unsigned int u32;

#define MFMA16 __builtin_amdgcn_mfma_f32_16x16x32_bf16

__device__ __forceinline__ float b2f(us u) {
  union { unsigned int i; float f; } x; x.i = ((unsigned int)u) << 16; return x.f;
}
__device__ __forceinline__ us f2b(float f) {
  union { float f; unsigned int i; } x; x.f = f;
  unsigned int r = x.i + 0x7fffu + ((x.i >> 16) & 1u);
  return (us)(r >> 16);
}
__device__ __forceinline__ float lrelu(float v) { return v > 0.f ? v : 0.01f * v; }
__device__ __forceinline__ bf16x8 ld8(const us* p) { return *reinterpret_cast<const bf16x8*>(p); }
// XOR swizzle for 64x320 bf16 LDS panels (row pitch 640 B = 160 words ≡ 0 mod 32 banks).
__device__ __forceinline__ int swz(int row) { return (row & 7) << 4; }

// ---------------- prep: weights -> bf16 [320][320] panels, c2 = Wr2 @ root ----------------
__global__ __launch_bounds__(256) void k_prep(
    const float* __restrict__ Ws, const float* __restrict__ Wp, const float* __restrict__ Wc,
    const float* __restrict__ Wr, const float* __restrict__ root,
    us* __restrict__ Wsb, us* __restrict__ Wpb, us* __restrict__ Wcb,
    us* __restrict__ Wr3b, float* __restrict__ c2) {
  int task = blockIdx.y;
  int gid = blockIdx.x * 256 + threadIdx.x;
  const int stride = 240 * 256;
  if (task < 3) {
    const float* src = (task == 0) ? Ws : (task == 1) ? Wp : Wc;
    us* dst = (task == 0) ? Wsb : (task == 1) ? Wpb : Wcb;
    for (int i = gid; i < 320 * 320; i += stride) {
      int r = i / 320, c = i - r * 320;
      dst[i] = (r < 300 && c < 300) ? f2b(src[r * 300 + c]) : (us)0;
    }
  } else if (task == 3) {
    // Wr [300][900] -> three [320][320] panels (seg 0/1/2 = enc/agg/tmp3 slices)
    for (int i = gid; i < 3 * 320 * 320; i += stride) {
      int seg = i / 102400, rem = i - seg * 102400;
      int r = rem / 320, c = rem - r * 320;
      Wr3b[i] = (r < 300 && c < 300) ? f2b(Wr[r * 900 + seg * 300 + c]) : (us)0;
    }
  } else {
    // c2[c] = sum_h Wr2[c][h] * root[h], padded to 320
    for (int i = gid; i < 320 * 8; i += stride) {
      int c = i >> 3, p = i & 7;
      float s = 0.f;
      if (c < 300)
        for (int h = p; h < 300; h += 8) s = fmaf(Wr[c * 900 + 300 + h], root[h], s);
      s += __shfl_xor(s, 1); s += __shfl_xor(s, 2); s += __shfl_xor(s, 4);
      if (p == 0) c2[c] = s;
    }
  }
}

// ---------------- core sweep: M row-tiles from swizzled LDS, B from global [320][320] ------
template<int M, int NT, int KS>
__device__ __forceinline__ void sweepM(const us* __restrict__ Alds, const int (&rr)[M],
    int q, int lo, const us* __restrict__ Bg, int n0, f32x4 (&acc)[M][NT]) {
  const char* ab = (const char*)Alds;
  int ao[M], sw[M];
#pragma unroll
  for (int m = 0; m < M; ++m) { ao[m] = rr[m] * 640; sw[m] = swz(rr[m]); }
  const us* br[NT];
#pragma unroll
  for (int t = 0; t < NT; ++t)
    br[t] = Bg + (long)((n0 + t) * 16 + lo) * 320 + 8 * q;
  bf16x8 aC[M], aN[M], b0[NT], b1[NT];
#pragma unroll
  for (int m = 0; m < M; ++m) {
    aC[m] = *(const bf16x8*)(ab + ao[m] + ((16 * q) ^ sw[m]));
    aN[m] = *(const bf16x8*)(ab + ao[m] + ((64 + 16 * q) ^ sw[m]));
  }
#pragma unroll
  for (int t = 0; t < NT; ++t) b0[t] = ld8(br[t]);
#pragma unroll
  for (int t = 0; t < NT; ++t) b1[t] = ld8(br[t] + 32);
#pragma unroll
  for (int ks = 0; ks < KS - 2; ++ks) {
    bf16x8 aF[M], bF[NT];
    const int kb = 64 * (ks + 2) + 16 * q;
#pragma unroll
    for (int m = 0; m < M; ++m) aF[m] = *(const bf16x8*)(ab + ao[m] + (kb ^ sw[m]));
#pragma unroll
    for (int t = 0; t < NT; ++t) bF[t] = ld8(br[t] + (ks + 2) * 32);
#pragma unroll
    for (int t = 0; t < NT; ++t)
#pragma unroll
      for (int m = 0; m < M; ++m)
        acc[m][t] = MFMA16(aC[m], b0[t], acc[m][t], 0, 0, 0);
#pragma unroll
    for (int m = 0; m < M; ++m) { aC[m] = aN[m]; aN[m] = aF[m]; }
#pragma unroll
    for (int t = 0; t < NT; ++t) { b0[t] = b1[t]; b1[t] = bF[t]; }
  }
#pragma unroll
  for (int t = 0; t < NT; ++t)
#pragma unroll
    for (int m = 0; m < M; ++m) acc[m][t] = MFMA16(aC[m], b0[t], acc[m][t], 0, 0, 0);
#pragma unroll
  for (int t = 0; t < NT; ++t)
#pragma unroll
    for (int m = 0; m < M; ++m) acc[m][t] = MFMA16(aN[m], b1[t], acc[m][t], 0, 0, 0);
}

// epilogue (2 row-tiles): acc -> lrelu(+bias) -> bf16 into swizzled 64x320 panel
__device__ __forceinline__ void epi_lds(const f32x4 (&acc)[2][5], const float* __restrict__ bias,
    us* __restrict__ dst, int mh, int nq, int lo, int q) {
#pragma unroll
  for (int mi = 0; mi < 2; ++mi)
#pragma unroll
    for (int tt = 0; tt < 5; ++tt) {
      int col = (nq * 5 + tt) * 16 + lo;
      if (col < 300) {
        float bb = bias[col];
#pragma unroll
        for (int r = 0; r < 4; ++r) {
          int row = (mh * 2 + mi) * 16 + 4 * q + r;
          *(us*)((char*)dst + row * 640 + ((2 * col) ^ swz(row))) =
              f2b(lrelu(acc[mi][tt][r] + bb));
        }
      }
    }
}

// epilogue (1 row-tile, 16-wave decomposition)
__device__ __forceinline__ void epi1(const f32x4 (&acc)[5], const float* __restrict__ bias,
    us* __restrict__ dst, int mg, int nq, int lo, int q) {
#pragma unroll
  for (int tt = 0; tt < 5; ++tt) {
    int col = (nq * 5 + tt) * 16 + lo;
    if (col < 300) {
      float bb = bias[col];
#pragma unroll
      for (int r = 0; r < 4; ++r) {
        int row = mg * 16 + 4 * q + r;
        *(us*)((char*)dst + row * 640 + ((2 * col) ^ swz(row))) =
            f2b(lrelu(acc[tt][r] + bb));
      }
    }
  }
}

// ---------------- mega: one block per document, 16 waves, everything in LDS ----------------
__global__ __launch_bounds__(1024) void k_mega(
    const int* __restrict__ wi, const float* __restrict__ E,
    const us* __restrict__ Wsb, const us* __restrict__ Wpb, const us* __restrict__ Wcb,
    const us* __restrict__ Wrb, const float* __restrict__ c2,
    const float* __restrict__ b_sent, const float* __restrict__ b_par,
    const float* __restrict__ b_ch,
    const float* __restrict__ w_root, const float* __restrict__ b_root,
    const float* __restrict__ b_r, const float* __restrict__ W_cls,
    const float* __restrict__ b_cls,
    float* __restrict__ outp, float* __restrict__ outA, float* __restrict__ outF) {
  __shared__ __align__(16) us BIG[61440];        // 3 x [64][320] bf16 panels (122880 B)
  __shared__ __align__(16) float LA[64 * 68];    // logits / A fp32 (17408 B)
  __shared__ __align__(16) us AtL[64 * 72];      // A^T bf16, pitch 72 (9216 B)
  __shared__ float pm[512], ps[512];             // softmax partials (4096 B)
  __shared__ float scS[64], friS[64], rsS[64];
  __shared__ float finP2[4 * 320];               // per-m-tile column sums (5120 B)

  const int d = blockIdx.x, t = threadIdx.x;
  const int w = t >> 6, lane = t & 63, lo = lane & 15, q = lane >> 4;
  const int mg = w & 3, nq = w >> 2;             // 16-wave: 4 m-tiles x 4 n-quarters
  const f32x4 z4 = {0.f, 0.f, 0.f, 0.f};
  us* const Pl = BIG + 20480;
  us* const Cl = BIG + 40960;
  us* const G2T = BIG + 20480;                   // [320][72] bf16, reuses P+C space

  // phase 0: clear pad tail bytes [512,640) of every panel row (covers cols 256..319
  // under the within-row swizzle; real cols 256..299 are rewritten later)
  for (int i = t; i < 6144; i += 1024) {
    int p = i >> 11, rem = i & 2047, r = rem >> 5, wd = rem & 31;
    *(u32*)((char*)BIG + p * 40960 + r * 640 + 512 + wd * 4) = 0u;
  }
  __syncthreads();

  // phase 1: gather x_last = E[wi[d, s, 63]] -> panel 0 (swizzled bf16)
  {
    int s = t >> 4, p = t & 15;
    int widx = wi[((d * 64 + s) << 6) + 63];
    const float4* er = (const float4*)(E + (long)widx * 300);
    char* rowb = (char*)BIG + s * 640;
    int sw = swz(s);
    for (int j = p; j < 75; j += 16) {
      float4 v = er[j];
      *(ushort4*)(rowb + ((8 * j) ^ sw)) =
          make_ushort4(f2b(v.x), f2b(v.y), f2b(v.z), f2b(v.w));
    }
  }
  __syncthreads();

  // phase 2: enc = lrelu(x @ Ws^T + b), in place over x (16 waves, 1 sweep)
  {
    int rr[1] = { mg * 16 + lo };
    f32x4 acc[1][5];
#pragma unroll
    for (int b = 0; b < 5; ++b) acc[0][b] = z4;
    sweepM<1, 5, 10>(BIG, rr, q, lo, Wsb, nq * 5, acc);
    __syncthreads();               // all reads of x done before overwrite
    epi1(acc[0], b_sent, BIG, mg, nq, lo, q);
  }
  __syncthreads();

  // phase 2b: scores = enc @ w_root + b_root (16 lanes per row)
  {
    int i = t >> 4, p = t & 15;
    float s = 0.f;
    for (int cch = p; cch < 38; cch += 16) {
      bf16x8 v = *(const bf16x8*)((const char*)BIG + i * 640 + ((16 * cch) ^ swz(i)));
#pragma unroll
      for (int e = 0; e < 8; ++e) {
        int h = cch * 8 + e;
        if (h < 300) s = fmaf(b2f((us)v[e]), w_root[h], s);
      }
    }
    s += __shfl_xor(s, 1); s += __shfl_xor(s, 2); s += __shfl_xor(s, 4); s += __shfl_xor(s, 8);
    if (p == 0) scS[i] = s + b_root[0];
  }
  // no barrier: phase 3 below only reads enc / writes P,C; scS consumed after barrier

  // phase 3: waves 0-7 -> P, waves 8-15 -> C (one sweep-time)
  {
    int w2 = w & 7, mh = w2 & 1, nqq = w2 >> 1;
    int rr[2] = { mh * 32 + lo, mh * 32 + 16 + lo };
    const us* Bg = (w < 8) ? Wpb : Wcb;
    const float* bias = (w < 8) ? b_par : b_ch;
    us* dst = (w < 8) ? Pl : Cl;
    f32x4 acc[2][5];
#pragma unroll
    for (int a = 0; a < 2; ++a)
#pragma unroll
      for (int b = 0; b < 5; ++b) acc[a][b] = z4;
    sweepM<2, 5, 10>(BIG, rr, q, lo, Bg, nqq * 5, acc);
    epi_lds(acc, bias, dst, mh, nqq, lo, q);
  }
  __syncthreads();

  // fri = softmax(scores) (wave 0 head; runs before it starts logits)
  if (t < 64) {
    float sc = scS[t], m = sc;
#pragma unroll
    for (int o = 32; o > 0; o >>= 1) m = fmaxf(m, __shfl_xor(m, o));
    float e = expf(sc - m), sum = e;
#pragma unroll
    for (int o = 32; o > 0; o >>= 1) sum += __shfl_xor(sum, o);
    float f = e / sum;
    friS[t] = f;
    outF[d * 64 + t] = f;
  }

  // phase 4|5 overlapped: waves 0-7 logits L = P @ C^T; waves 8-15 G2e = enc @ Wr2^T (regs)
  f32x4 g2acc[2][5];
  if (w < 8) {
    int m = w >> 1, np = (w & 1) * 2;
    int arow = m * 16 + lo;
    int brow0 = np * 16 + lo, brow1 = brow0 + 16;
    int sa = swz(arow), sb0 = swz(brow0), sb1 = swz(brow1);
    f32x4 a0 = z4, a1 = z4;
#pragma unroll
    for (int ks = 0; ks < 10; ++ks) {
      int kb = 64 * ks + 16 * q;
      bf16x8 av  = *(const bf16x8*)((const char*)Pl + arow * 640 + (kb ^ sa));
      bf16x8 bv0 = *(const bf16x8*)((const char*)Cl + brow0 * 640 + (kb ^ sb0));
      bf16x8 bv1 = *(const bf16x8*)((const char*)Cl + brow1 * 640 + (kb ^ sb1));
      a0 = MFMA16(av, bv0, a0, 0, 0, 0);
      a1 = MFMA16(av, bv1, a1, 0, 0, 0);
    }
#pragma unroll
    for (int r = 0; r < 4; ++r) {
      int row = m * 16 + 4 * q + r;
      int c0 = np * 16 + lo, c1 = c0 + 16;
      LA[row * 68 + c0] = (row == c0) ? NEG_INF : a0[r];
      LA[row * 68 + c1] = (row == c1) ? NEG_INF : a1[r];
    }
  } else {
    int w2 = w - 8, mh = w2 & 1, nqq = w2 >> 1;
    int rr[2] = { mh * 32 + lo, mh * 32 + 16 + lo };
#pragma unroll
    for (int a = 0; a < 2; ++a)
#pragma unroll
      for (int b = 0; b < 5; ++b) g2acc[a][b] = z4;
    sweepM<2, 5, 10>(BIG, rr, q, lo, Wrb + 102400, nqq * 5, g2acc);
  }
  __syncthreads();   // LA complete; P/C dead -> G2T region free

  // phase 4b softmax (waves 0-7) overlapped with G2T store (waves 8-15)
  {
    int j = lane, p2 = w;
    float ev[8], gm = 0.f;
    if (w < 8) {
      float mx = -3.0e38f;
#pragma unroll
      for (int ii = 0; ii < 8; ++ii) mx = fmaxf(mx, LA[(p2 * 8 + ii) * 68 + j]);
      pm[p2 * 64 + j] = mx;
    } else {
      int w2 = w - 8, mh = w2 & 1, nqq = w2 >> 1;
#pragma unroll
      for (int mi = 0; mi < 2; ++mi)
#pragma unroll
        for (int tt = 0; tt < 5; ++tt) {
          int col = (nqq * 5 + tt) * 16 + lo;
          if (col < 300)
#pragma unroll
            for (int r = 0; r < 4; ++r) {
              int row = (mh * 2 + mi) * 16 + 4 * q + r;
              G2T[col * 72 + row] = f2b(g2acc[mi][tt][r]);
            }
        }
      for (int i2 = t - 512; i2 < 720; i2 += 512)   // zero pad rows 300..319 of G2T
        ((u32*)(G2T + 21600))[i2] = 0u;
    }
    __syncthreads();
    float ssum = 0.f;
    if (w < 8) {
      gm = pm[j];
#pragma unroll
      for (int k = 1; k < 8; ++k) gm = fmaxf(gm, pm[k * 64 + j]);
#pragma unroll
      for (int ii = 0; ii < 8; ++ii) {
        float e = expf(LA[(p2 * 8 + ii) * 68 + j] - gm);
        ev[ii] = e; ssum += e;
      }
      ps[p2 * 64 + j] = ssum;
    }
    __syncthreads();
    if (w < 8) {
      float tot = ps[j];
#pragma unroll
      for (int k = 1; k < 8; ++k) tot += ps[k * 64 + j];
      float inv = 1.f / tot;
      float* Ad = outA + (long)d * 4096;
#pragma unroll
      for (int ii = 0; ii < 8; ++ii) {
        int i = p2 * 8 + ii;
        float a = ev[ii] * inv;
        Ad[i * 64 + j] = a;
        AtL[j * 72 + i] = f2b(a);
        LA[i * 68 + j] = a;
      }
    }
  }
  __syncthreads();
  if (t < 64) {   // rs[i] = sum_j A[i][j]
    float s = 0.f;
    for (int jj = 0; jj < 64; ++jj) s += LA[t * 68 + jj];
    rsS[t] = s;
  }
  __syncthreads();

  // phase 6: acc = rs*(enc@Wr3^T); += enc@Wr1^T; += A^T@G2e; lrelu(+b_r+fri*c2);
  //          column-reduced over sentences into finP2 (ri never materialized)
  {
    int rr[1] = { mg * 16 + lo };
    f32x4 am[1][5];
#pragma unroll
    for (int b = 0; b < 5; ++b) am[0][b] = z4;
    sweepM<1, 5, 10>(BIG, rr, q, lo, Wrb + 204800, nq * 5, am);   // G3 (tmp3 seg)
    // scale by rs (per output row) -> becomes the seed for G1 + G2r accumulation
#pragma unroll
    for (int tt = 0; tt < 5; ++tt)
#pragma unroll
      for (int r = 0; r < 4; ++r)
        am[0][tt][r] *= rsS[mg * 16 + 4 * q + r];
    sweepM<1, 5, 10>(BIG, rr, q, lo, Wrb, nq * 5, am);            // G1 (enc seg)
#pragma unroll
    for (int ks = 0; ks < 2; ++ks) {                              // G2r: A^T @ G2e, K=64
      bf16x8 aA = *(const bf16x8*)(AtL + (mg * 16 + lo) * 72 + 32 * ks + 8 * q);
#pragma unroll
      for (int tt = 0; tt < 5; ++tt) {
        bf16x8 bv = *(const bf16x8*)(G2T + ((nq * 5 + tt) * 16 + lo) * 72 + 32 * ks + 8 * q);
        am[0][tt] = MFMA16(aA, bv, am[0][tt], 0, 0, 0);
      }
    }
#pragma unroll
    for (int tt = 0; tt < 5; ++tt) {
      int col = (nq * 5 + tt) * 16 + lo;
      float bb = (col < 300) ? b_r[col] : 0.f;
      float cc = c2[col];
      float csum = 0.f;
#pragma unroll
      for (int r = 0; r < 4; ++r) {
        int i = mg * 16 + 4 * q + r;
        csum += lrelu(am[0][tt][r] + friS[i] * cc + bb);
      }
      csum += __shfl_xor(csum, 16);
      csum += __shfl_xor(csum, 32);
      if (q == 0) finP2[mg * 320 + col] = csum;   // sum over this m-tile's 16 sentences
    }
  }
  __syncthreads();

  // phase 7: out = (mean_i ri) @ W_cls^T + b_cls
  if (t < 128) {
    int cls = t >> 6, ln = t & 63;
    float s = 0.f;
    for (int h = ln; h < 300; h += 64)
      s += (finP2[h] + finP2[320 + h] + finP2[640 + h] + finP2[960 + h]) *
           W_cls[cls * 300 + h];
#pragma unroll
    for (int o = 32; o > 0; o >>= 1) s += __shfl_xor(s, o);
    if (ln == 0) outp[d * 2 + cls] = s * 0.015625f + b_cls[cls];
  }
}

extern "C" void kernel_launch(void* const* d_in, const int* in_sizes, int n_in,
                              void* d_out, int out_size, void* d_ws, size_t ws_size,
                              hipStream_t stream) {
  const int*   wi     = (const int*)d_in[0];
  const float* E      = (const float*)d_in[1];
  const float* W_sent = (const float*)d_in[2];
  const float* b_sent = (const float*)d_in[3];
  const float* W_par  = (const float*)d_in[4];
  const float* b_par  = (const float*)d_in[5];
  const float* W_ch   = (const float*)d_in[6];
  const float* b_ch   = (const float*)d_in[7];
  const float* w_root = (const float*)d_in[8];
  const float* b_root = (const float*)d_in[9];
  const float* root_e = (const float*)d_in[10];
  const float* W_r    = (const float*)d_in[11];
  const float* b_r    = (const float*)d_in[12];
  const float* W_cls  = (const float*)d_in[13];
  const float* b_cls  = (const float*)d_in[14];

  us* B = (us*)d_ws;
  us* Wsb  = B;                     // 102400  [320][320] bf16
  us* Wpb  = B + 102400;
  us* Wcb  = B + 204800;
  us* Wr3b = B + 307200;            // 3 x [320][320] bf16 (seg0/1/2)
  float* c2 = (float*)(B + 614400); // [320] fp32 = Wr2 @ root (padded)

  float* outp = (float*)d_out;      // [out(128) | A(262144) | fri(4096)]
  float* outA = outp + 128;
  float* outF = outp + 128 + 262144;

  k_prep<<<dim3(240, 5), 256, 0, stream>>>(W_sent, W_par, W_ch, W_r, root_e,
                                           Wsb, Wpb, Wcb, Wr3b, c2);
  k_mega<<<64, 1024, 0, stream>>>(wi, E, Wsb, Wpb, Wcb, Wr3b, c2,
                                  b_sent, b_par, b_ch, w_root, b_root,
                                  b_r, W_cls, b_cls, outp, outA, outF);
}

// Round 3
// 189.413 us; speedup vs baseline: 1.3342x; 1.3342x over previous
//
#include <hip/hip_runtime.h>

#define NEG_INF (-9999999.0f)

typedef __attribute__((ext_vector_type(8))) short bf16x8;
typedef __attribute__((ext_vector_type(4))) float f32x4;
typedef unsigned short us;
typedef unsigned int u32;

#define MFMA16 __builtin_amdgcn_mfma_f32_16x16x32_bf16

__device__ __forceinline__ float b2f(us u) {
  union { unsigned int i; float f; } x; x.i = ((unsigned int)u) << 16; return x.f;
}
__device__ __forceinline__ us f2b(float f) {
  union { float f; unsigned int i; } x; x.f = f;
  unsigned int r = x.i + 0x7fffu + ((x.i >> 16) & 1u);
  return (us)(r >> 16);
}
__device__ __forceinline__ float lrelu(float v) { return v > 0.f ? v : 0.01f * v; }
__device__ __forceinline__ bf16x8 ld8(const us* p) { return *reinterpret_cast<const bf16x8*>(p); }
// XOR swizzle for 16-row x 320-col bf16 LDS panels (row pitch 640 B).
__device__ __forceinline__ int swz(int row) { return (row & 7) << 4; }

// ---------------- prep: weights -> bf16 [320][320] panels, c2 = Wr2 @ root ----------------
__global__ __launch_bounds__(256) void k_prep(
    const float* __restrict__ Ws, const float* __restrict__ Wp, const float* __restrict__ Wc,
    const float* __restrict__ Wr, const float* __restrict__ root,
    us* __restrict__ Wsb, us* __restrict__ Wpb, us* __restrict__ Wcb,
    us* __restrict__ Wr3b, float* __restrict__ c2) {
  int task = blockIdx.y;
  int gid = blockIdx.x * 256 + threadIdx.x;
  const int stride = 240 * 256;
  if (task < 3) {
    const float* src = (task == 0) ? Ws : (task == 1) ? Wp : Wc;
    us* dst = (task == 0) ? Wsb : (task == 1) ? Wpb : Wcb;
    for (int i = gid; i < 320 * 320; i += stride) {
      int r = i / 320, c = i - r * 320;
      dst[i] = (r < 300 && c < 300) ? f2b(src[r * 300 + c]) : (us)0;
    }
  } else if (task == 3) {
    for (int i = gid; i < 3 * 320 * 320; i += stride) {
      int seg = i / 102400, rem = i - seg * 102400;
      int r = rem / 320, c = rem - r * 320;
      Wr3b[i] = (r < 300 && c < 300) ? f2b(Wr[r * 900 + seg * 300 + c]) : (us)0;
    }
  } else {
    for (int i = gid; i < 320 * 8; i += stride) {
      int c = i >> 3, p = i & 7;
      float s = 0.f;
      if (c < 300)
        for (int h = p; h < 300; h += 8) s = fmaf(Wr[c * 900 + 300 + h], root[h], s);
      s += __shfl_xor(s, 1); s += __shfl_xor(s, 2); s += __shfl_xor(s, 4);
      if (p == 0) c2[c] = s;
    }
  }
}

// ------- sweepM: A rows from swizzled 16x320 LDS, B rows from global [320][320] (depth-2) --
template<int M, int NT, int KS>
__device__ __forceinline__ void sweepM(const us* __restrict__ Alds, const int (&rr)[M],
    int q, int lo, const us* __restrict__ Bg, int n0, f32x4 (&acc)[M][NT]) {
  const char* ab = (const char*)Alds;
  int ao[M], sw[M];
#pragma unroll
  for (int m = 0; m < M; ++m) { ao[m] = rr[m] * 640; sw[m] = swz(rr[m]); }
  const us* br[NT];
#pragma unroll
  for (int t = 0; t < NT; ++t)
    br[t] = Bg + (long)((n0 + t) * 16 + lo) * 320 + 8 * q;
  bf16x8 aC[M], aN[M], b0[NT], b1[NT];
#pragma unroll
  for (int m = 0; m < M; ++m) {
    aC[m] = *(const bf16x8*)(ab + ao[m] + ((16 * q) ^ sw[m]));
    aN[m] = *(const bf16x8*)(ab + ao[m] + ((64 + 16 * q) ^ sw[m]));
  }
#pragma unroll
  for (int t = 0; t < NT; ++t) b0[t] = ld8(br[t]);
#pragma unroll
  for (int t = 0; t < NT; ++t) b1[t] = ld8(br[t] + 32);
#pragma unroll
  for (int ks = 0; ks < KS - 2; ++ks) {
    bf16x8 aF[M], bF[NT];
    const int kb = 64 * (ks + 2) + 16 * q;
#pragma unroll
    for (int m = 0; m < M; ++m) aF[m] = *(const bf16x8*)(ab + ao[m] + (kb ^ sw[m]));
#pragma unroll
    for (int t = 0; t < NT; ++t) bF[t] = ld8(br[t] + (ks + 2) * 32);
#pragma unroll
    for (int t = 0; t < NT; ++t)
#pragma unroll
      for (int m = 0; m < M; ++m)
        acc[m][t] = MFMA16(aC[m], b0[t], acc[m][t], 0, 0, 0);
#pragma unroll
    for (int m = 0; m < M; ++m) { aC[m] = aN[m]; aN[m] = aF[m]; }
#pragma unroll
    for (int t = 0; t < NT; ++t) { b0[t] = b1[t]; b1[t] = bF[t]; }
  }
#pragma unroll
  for (int t = 0; t < NT; ++t)
#pragma unroll
    for (int m = 0; m < M; ++m) acc[m][t] = MFMA16(aC[m], b0[t], acc[m][t], 0, 0, 0);
#pragma unroll
  for (int t = 0; t < NT; ++t)
#pragma unroll
    for (int m = 0; m < M; ++m) acc[m][t] = MFMA16(aN[m], b1[t], acc[m][t], 0, 0, 0);
}

// ------- sweepT: A-operand (output rows = h) from global rows, B from LDS enc rows --------
template<int NT, int KS>
__device__ __forceinline__ void sweepT(const us* __restrict__ es, int q, int lo,
    const us* __restrict__ Ag, int n0, f32x4 (&acc)[NT]) {
  const char* eb = (const char*)es;
  const int bo = lo * 640, sb = swz(lo);
  const us* ar[NT];
#pragma unroll
  for (int t = 0; t < NT; ++t)
    ar[t] = Ag + (long)((n0 + t) * 16 + lo) * 320 + 8 * q;
  bf16x8 a0[NT], a1[NT];
#pragma unroll
  for (int t = 0; t < NT; ++t) a0[t] = ld8(ar[t]);
  bf16x8 b0 = *(const bf16x8*)(eb + bo + ((16 * q) ^ sb));
#pragma unroll
  for (int t = 0; t < NT; ++t) a1[t] = ld8(ar[t] + 32);
  bf16x8 b1 = *(const bf16x8*)(eb + bo + ((64 + 16 * q) ^ sb));
#pragma unroll
  for (int ks = 0; ks < KS - 2; ++ks) {
    bf16x8 a2[NT];
#pragma unroll
    for (int t = 0; t < NT; ++t) a2[t] = ld8(ar[t] + (ks + 2) * 32);
    bf16x8 b2 = *(const bf16x8*)(eb + bo + ((64 * (ks + 2) + 16 * q) ^ sb));
#pragma unroll
    for (int t = 0; t < NT; ++t) acc[t] = MFMA16(a0[t], b0, acc[t], 0, 0, 0);
#pragma unroll
    for (int t = 0; t < NT; ++t) { a0[t] = a1[t]; a1[t] = a2[t]; }
    b0 = b1; b1 = b2;
  }
#pragma unroll
  for (int t = 0; t < NT; ++t) acc[t] = MFMA16(a0[t], b0, acc[t], 0, 0, 0);
#pragma unroll
  for (int t = 0; t < NT; ++t) acc[t] = MFMA16(a1[t], b1, acc[t], 0, 0, 0);
}

// ------- sweepG: both operands from global (depth-2) — for k_doc logits ----------
template<int NT>
__device__ __forceinline__ void sweepG(const us* __restrict__ Ab,
    const us* __restrict__ Bb, int m0, int nt0, int lo, int q, int ksn, f32x4* acc) {
  const us* ar = Ab + (long)(m0 + lo) * 320 + 8 * q;
  const us* br[NT];
#pragma unroll
  for (int t = 0; t < NT; ++t)
    br[t] = Bb + (long)((nt0 + t) * 16 + lo) * 320 + 8 * q;
  bf16x8 a0 = ld8(ar), a1 = ld8(ar + 32);
  bf16x8 b0[NT], b1[NT];
#pragma unroll
  for (int t = 0; t < NT; ++t) b0[t] = ld8(br[t]);
#pragma unroll
  for (int t = 0; t < NT; ++t) b1[t] = ld8(br[t] + 32);
  for (int ks = 0; ks < ksn - 2; ++ks) {
    bf16x8 a2 = ld8(ar + (ks + 2) * 32);
    bf16x8 b2[NT];
#pragma unroll
    for (int t = 0; t < NT; ++t) b2[t] = ld8(br[t] + (ks + 2) * 32);
#pragma unroll
    for (int t = 0; t < NT; ++t)
      acc[t] = MFMA16(a0, b0[t], acc[t], 0, 0, 0);
    a0 = a1; a1 = a2;
#pragma unroll
    for (int t = 0; t < NT; ++t) { b0[t] = b1[t]; b1[t] = b2[t]; }
  }
#pragma unroll
  for (int t = 0; t < NT; ++t)
    acc[t] = MFMA16(a0, b0[t], acc[t], 0, 0, 0);
#pragma unroll
  for (int t = 0; t < NT; ++t)
    acc[t] = MFMA16(a1, b1[t], acc[t], 0, 0, 0);
}

// ---------------- K1a: gather x_last, enc = lrelu(x@Ws^T+b), scores ----------------
__global__ __launch_bounds__(256) void k_enc(
    const int* __restrict__ wi, const float* __restrict__ E,
    const us* __restrict__ Wsb, const float* __restrict__ b_sent,
    const float* __restrict__ w_root,
    us* __restrict__ encG, float* __restrict__ scG) {
  __shared__ __align__(16) us xs[16 * 320];
  __shared__ __align__(16) us es[16 * 320];
  int t = threadIdx.x;
  int r0g = blockIdx.x * 16;
  {
    int row = t >> 4, p = t & 15;
    int widx = wi[((r0g + row) << 6) + 63];
    const float4* er = (const float4*)(E + (long)widx * 300);
    char* rowb = (char*)xs + row * 640;
    int sw = swz(row);
    for (int j = p; j < 75; j += 16) {
      float4 v = er[j];
      *(ushort4*)(rowb + ((8 * j) ^ sw)) =
          make_ushort4(f2b(v.x), f2b(v.y), f2b(v.z), f2b(v.w));
    }
    // zero K-pad cols 300..319 (sweep reads them; garbage could be NaN)
    for (int c = 300 + p; c < 320; c += 16)
      *(us*)(rowb + ((2 * c) ^ sw)) = 0;
  }
  __syncthreads();
  int w = t >> 6, lane = t & 63, lo = lane & 15, q = lane >> 4;
  const f32x4 z4 = {0.f, 0.f, 0.f, 0.f};
  int rr[1] = { lo };
  f32x4 acc[1][5];
#pragma unroll
  for (int b = 0; b < 5; ++b) acc[0][b] = z4;
  sweepM<1, 5, 10>(xs, rr, q, lo, Wsb, w * 5, acc);
#pragma unroll
  for (int tt = 0; tt < 5; ++tt) {
    int col = (w * 5 + tt) * 16 + lo;
    float bb = (col < 300) ? b_sent[col] : 0.f;
#pragma unroll
    for (int r = 0; r < 4; ++r) {
      int row = 4 * q + r;
      us hv = (col < 300) ? f2b(lrelu(acc[0][tt][r] + bb)) : (us)0;
      *(us*)((char*)es + row * 640 + ((2 * col) ^ swz(row))) = hv;
      encG[(long)(r0g + row) * 320 + col] = hv;
    }
  }
  __syncthreads();
  // scores = enc @ w_root (b_root omitted: softmax-invariant, exactly cancels)
  {
    int row = t >> 4, p = t & 15;
    float s = 0.f;
    for (int cch = p; cch < 38; cch += 16) {
      bf16x8 v = *(const bf16x8*)((const char*)es + row * 640 + ((16 * cch) ^ swz(row)));
#pragma unroll
      for (int e = 0; e < 8; ++e) {
        int h = cch * 8 + e;
        if (h < 300) s = fmaf(b2f((us)v[e]), w_root[h], s);
      }
    }
    s += __shfl_xor(s, 1); s += __shfl_xor(s, 2); s += __shfl_xor(s, 4); s += __shfl_xor(s, 8);
    if (p == 0) scG[r0g + row] = s;
  }
}

// ---------------- K1b: 256 row-tiles x 5 tasks {P, C, G1, G3, G2eT} ----------------
__global__ __launch_bounds__(256) void k_panels(
    const us* __restrict__ encG,
    const us* __restrict__ Wpb, const us* __restrict__ Wcb, const us* __restrict__ Wrb,
    const float* __restrict__ b_par, const float* __restrict__ b_ch,
    us* __restrict__ Pg, us* __restrict__ Cg, us* __restrict__ G1g, us* __restrict__ G3g,
    us* __restrict__ G2eT) {
  __shared__ __align__(16) us es[16 * 320];
  int t = threadIdx.x, task = blockIdx.y, rt = blockIdx.x;
  // stage enc tile (pad cols already zero in encG), swizzled
  {
    const float4* src = (const float4*)(encG + (long)rt * 16 * 320);
    for (int i = t; i < 640; i += 256) {
      int row = i / 40, c16 = i - row * 40;
      float4 v = src[i];
      *(float4*)((char*)es + row * 640 + ((c16 * 16) ^ swz(row))) = v;
    }
  }
  __syncthreads();
  int w = t >> 6, lane = t & 63, lo = lane & 15, q = lane >> 4;
  const f32x4 z4 = {0.f, 0.f, 0.f, 0.f};
  if (task == 4) {
    // G2eT[h][row] = (enc @ Wr2^T)^T : A-operand = Wr2 rows (h), B = enc rows (LDS)
    f32x4 acc[5];
#pragma unroll
    for (int b = 0; b < 5; ++b) acc[b] = z4;
    sweepT<5, 10>(es, q, lo, Wrb + 102400, w * 5, acc);
#pragma unroll
    for (int tt = 0; tt < 5; ++tt)
#pragma unroll
      for (int r = 0; r < 4; ++r) {
        int h = (w * 5 + tt) * 16 + 4 * q + r;
        G2eT[(long)h * 4096 + rt * 16 + lo] = (h < 300) ? f2b(acc[tt][r]) : (us)0;
      }
  } else {
    const us* Bg = (task == 0) ? Wpb : (task == 1) ? Wcb : (task == 2) ? Wrb : Wrb + 204800;
    int rr[1] = { lo };
    f32x4 acc[1][5];
#pragma unroll
    for (int b = 0; b < 5; ++b) acc[0][b] = z4;
    sweepM<1, 5, 10>(es, rr, q, lo, Bg, w * 5, acc);
    if (task < 2) {
      const float* bias = (task == 0) ? b_par : b_ch;
      us* outb = (task == 0) ? Pg : Cg;
#pragma unroll
      for (int tt = 0; tt < 5; ++tt) {
        int col = (w * 5 + tt) * 16 + lo;
        float bb = (col < 300) ? bias[col] : 0.f;
#pragma unroll
        for (int r = 0; r < 4; ++r) {
          int row = rt * 16 + 4 * q + r;
          outb[(long)row * 320 + col] =
              (col < 300) ? f2b(lrelu(acc[0][tt][r] + bb)) : (us)0;
        }
      }
    } else {
      us* outb = (task == 2) ? G1g : G3g;
#pragma unroll
      for (int tt = 0; tt < 5; ++tt) {
        int col = (w * 5 + tt) * 16 + lo;
        if (col < 300)
#pragma unroll
          for (int r = 0; r < 4; ++r)
            outb[(long)(rt * 16 + 4 * q + r) * 320 + col] = f2b(acc[0][tt][r]);
      }
    }
  }
}

// ---------------- K2: per-doc logits, softmax, A/fri out, G2r, combine, out ----------------
__global__ __launch_bounds__(512) void k_doc(
    const us* __restrict__ Pg, const us* __restrict__ Cg, const us* __restrict__ G2eT,
    const us* __restrict__ G1g, const us* __restrict__ G3g,
    const float* __restrict__ scG, const float* __restrict__ c2,
    const float* __restrict__ b_r, const float* __restrict__ W_cls,
    const float* __restrict__ b_cls,
    float* __restrict__ outp, float* __restrict__ outA, float* __restrict__ outF) {
  __shared__ __align__(16) float LA[64 * 68];
  __shared__ __align__(16) us AtL[64 * 72];
  __shared__ float pm[512], ps[512];
  __shared__ float friS[64], rsS[64];
  __shared__ float finP2[4 * 320];
  int d = blockIdx.x, t = threadIdx.x;
  int w = t >> 6, lane = t & 63, lo = lane & 15, q = lane >> 4;
  const f32x4 z4 = {0.f, 0.f, 0.f, 0.f};

  if (t < 64) {    // fri = softmax(scores)
    float sc = scG[d * 64 + t], m = sc;
#pragma unroll
    for (int o = 32; o > 0; o >>= 1) m = fmaxf(m, __shfl_xor(m, o));
    float e = expf(sc - m), sum = e;
#pragma unroll
    for (int o = 32; o > 0; o >>= 1) sum += __shfl_xor(sum, o);
    float f = e / sum;
    friS[t] = f;
    outF[d * 64 + t] = f;
  }

  // logits L = P @ C^T (64x64, K=320); wave w -> (m = w>>1, 2 n-tiles at (w&1)*2)
  {
    const us* Pd = Pg + (long)d * 64 * 320;
    const us* Cd = Cg + (long)d * 64 * 320;
    int m = w >> 1, np = (w & 1) * 2;
    f32x4 acc2[2] = { z4, z4 };
    sweepG<2>(Pd, Cd, m * 16, np, lo, q, 10, acc2);
#pragma unroll
    for (int r = 0; r < 4; ++r) {
      int row = m * 16 + 4 * q + r;
      int c0 = np * 16 + lo, c1 = c0 + 16;
      LA[row * 68 + c0] = (row == c0) ? NEG_INF : acc2[0][r];
      LA[row * 68 + c1] = (row == c1) ? NEG_INF : acc2[1][r];
    }
  }
  __syncthreads();

  // column softmax over i for each j; write A (fp32), AtL (bf16 A-op layout), LA=a
  {
    int j = lane;
    float mx = -3.0e38f;
#pragma unroll
    for (int ii = 0; ii < 8; ++ii) mx = fmaxf(mx, LA[(w * 8 + ii) * 68 + j]);
    pm[w * 64 + j] = mx;
    __syncthreads();
    float gm = pm[j];
#pragma unroll
    for (int k = 1; k < 8; ++k) gm = fmaxf(gm, pm[k * 64 + j]);
    float ev[8], ss = 0.f;
#pragma unroll
    for (int ii = 0; ii < 8; ++ii) {
      float e = expf(LA[(w * 8 + ii) * 68 + j] - gm);
      ev[ii] = e; ss += e;
    }
    ps[w * 64 + j] = ss;
    __syncthreads();
    float tot = ps[j];
#pragma unroll
    for (int k = 1; k < 8; ++k) tot += ps[k * 64 + j];
    float inv = 1.f / tot;
    float* Ad = outA + (long)d * 4096;
#pragma unroll
    for (int ii = 0; ii < 8; ++ii) {
      int i = w * 8 + ii;
      float a = ev[ii] * inv;
      Ad[i * 64 + j] = a;
      AtL[j * 72 + i] = f2b(a);
      LA[i * 68 + j] = a;
    }
  }
  __syncthreads();
  if (t < 64) {   // rs[i] = sum_j A[i][j]
    float s = 0.f;
    for (int jj = 0; jj < 64; ++jj) s += LA[t * 68 + jj];
    rsS[t] = s;
  }
  __syncthreads();

  // G2r = A^T-weighted G2e (K=64) + combine + column-reduce over sentences
  {
    int mg = w & 3, nh = w >> 2;
    f32x4 a10[10];
#pragma unroll
    for (int b = 0; b < 10; ++b) a10[b] = z4;
#pragma unroll
    for (int ks = 0; ks < 2; ++ks) {
      bf16x8 aA = ld8(AtL + (mg * 16 + lo) * 72 + 32 * ks + 8 * q);
#pragma unroll
      for (int tt = 0; tt < 10; ++tt) {
        bf16x8 bv = ld8(G2eT + (long)((nh * 10 + tt) * 16 + lo) * 4096 +
                        d * 64 + 32 * ks + 8 * q);
        a10[tt] = MFMA16(aA, bv, a10[tt], 0, 0, 0);
      }
    }
#pragma unroll
    for (int tt = 0; tt < 10; ++tt) {
      int col = (nh * 10 + tt) * 16 + lo;
      if (col < 300) {
        float bb = b_r[col], cc = c2[col];
        float csum = 0.f;
#pragma unroll
        for (int r = 0; r < 4; ++r) {
          int i = mg * 16 + 4 * q + r;
          float g1 = b2f(G1g[(long)(d * 64 + i) * 320 + col]);
          float g3 = b2f(G3g[(long)(d * 64 + i) * 320 + col]);
          csum += lrelu(a10[tt][r] + g1 + rsS[i] * g3 + friS[i] * cc + bb);
        }
        csum += __shfl_xor(csum, 16);
        csum += __shfl_xor(csum, 32);
        if (q == 0) finP2[mg * 320 + col] = csum;
      }
    }
  }
  __syncthreads();

  if (t < 128) {   // out = (mean_i ri) @ W_cls^T + b_cls
    int cls = t >> 6, ln = t & 63;
    float s = 0.f;
    for (int h = ln; h < 300; h += 64)
      s += (finP2[h] + finP2[320 + h] + finP2[640 + h] + finP2[960 + h]) *
           W_cls[cls * 300 + h];
#pragma unroll
    for (int o = 32; o > 0; o >>= 1) s += __shfl_xor(s, o);
    if (ln == 0) outp[d * 2 + cls] = s * 0.015625f + b_cls[cls];
  }
}

extern "C" void kernel_launch(void* const* d_in, const int* in_sizes, int n_in,
                              void* d_out, int out_size, void* d_ws, size_t ws_size,
                              hipStream_t stream) {
  const int*   wi     = (const int*)d_in[0];
  const float* E      = (const float*)d_in[1];
  const float* W_sent = (const float*)d_in[2];
  const float* b_sent = (const float*)d_in[3];
  const float* W_par  = (const float*)d_in[4];
  const float* b_par  = (const float*)d_in[5];
  const float* W_ch   = (const float*)d_in[6];
  const float* b_ch   = (const float*)d_in[7];
  const float* w_root = (const float*)d_in[8];
  const float* b_root = (const float*)d_in[9];  (void)b_root;
  const float* root_e = (const float*)d_in[10];
  const float* W_r    = (const float*)d_in[11];
  const float* b_r    = (const float*)d_in[12];
  const float* W_cls  = (const float*)d_in[13];
  const float* b_cls  = (const float*)d_in[14];

  us* B = (us*)d_ws;
  us* Wsb   = B;                      // [320][320] bf16
  us* Wpb   = B + 102400;
  us* Wcb   = B + 204800;
  us* Wr3b  = B + 307200;             // 3 x [320][320] bf16
  float* c2 = (float*)(B + 614400);   // [320] fp32
  us* encG  = B + 615040;             // [4096][320] bf16
  us* Pg    = B + 1925760;
  us* Cg    = B + 3236480;
  us* G1g   = B + 4547200;
  us* G3g   = B + 5857920;
  us* G2eT  = B + 7168640;            // [320][4096] bf16 (transposed G2e)
  float* scG = (float*)(B + 8479360); // [4096] fp32 scores

  float* outp = (float*)d_out;        // [out(128) | A(262144) | fri(4096)]
  float* outA = outp + 128;
  float* outF = outp + 128 + 262144;

  k_prep<<<dim3(240, 5), 256, 0, stream>>>(W_sent, W_par, W_ch, W_r, root_e,
                                           Wsb, Wpb, Wcb, Wr3b, c2);
  k_enc<<<256, 256, 0, stream>>>(wi, E, Wsb, b_sent, w_root, encG, scG);
  k_panels<<<dim3(256, 5), 256, 0, stream>>>(encG, Wpb, Wcb, Wr3b,
                                             b_par, b_ch, Pg, Cg, G1g, G3g, G2eT);
  k_doc<<<64, 512, 0, stream>>>(Pg, Cg, G2eT, G1g, G3g, scG, c2,
                                b_r, W_cls, b_cls, outp, outA, outF);
}

// Round 4
// 174.054 us; speedup vs baseline: 1.4519x; 1.0882x over previous
//
#include <hip/hip_runtime.h>

#define NEG_INF (-9999999.0f)

typedef __attribute__((ext_vector_type(8))) short bf16x8;
typedef __attribute__((ext_vector_type(4))) float f32x4;
typedef unsigned short us;
typedef unsigned int u32;

#define MFMA16 __builtin_amdgcn_mfma_f32_16x16x32_bf16

__device__ __forceinline__ float b2f(us u) {
  union { unsigned int i; float f; } x; x.i = ((unsigned int)u) << 16; return x.f;
}
__device__ __forceinline__ us f2b(float f) {
  union { float f; unsigned int i; } x; x.f = f;
  unsigned int r = x.i + 0x7fffu + ((x.i >> 16) & 1u);
  return (us)(r >> 16);
}
__device__ __forceinline__ float lrelu(float v) { return v > 0.f ? v : 0.01f * v; }
__device__ __forceinline__ bf16x8 ld8(const us* p) { return *reinterpret_cast<const bf16x8*>(p); }
// XOR swizzle for N-row x 320-col bf16 LDS panels (row pitch 640 B).
__device__ __forceinline__ int swz(int row) { return (row & 7) << 4; }

// ---------------- prep0: Ws -> bf16 [320][320] (critical path only) ----------------
__global__ __launch_bounds__(256) void k_prep0(
    const float* __restrict__ Ws, us* __restrict__ Wsb) {
  int gid = blockIdx.x * 256 + threadIdx.x;
  for (int i = gid; i < 320 * 320; i += 128 * 256) {
    int r = i / 320, c = i - r * 320;
    Wsb[i] = (r < 300 && c < 300) ? f2b(Ws[r * 300 + c]) : (us)0;
  }
}

// ------- sweepM: A rows from swizzled LDS, B rows from global [320][320] (depth-2) --
template<int M, int NT, int KS>
__device__ __forceinline__ void sweepM(const us* __restrict__ Alds, const int (&rr)[M],
    int q, int lo, const us* __restrict__ Bg, int n0, f32x4 (&acc)[M][NT]) {
  const char* ab = (const char*)Alds;
  int ao[M], sw[M];
#pragma unroll
  for (int m = 0; m < M; ++m) { ao[m] = rr[m] * 640; sw[m] = swz(rr[m]); }
  const us* br[NT];
#pragma unroll
  for (int t = 0; t < NT; ++t)
    br[t] = Bg + (long)((n0 + t) * 16 + lo) * 320 + 8 * q;
  bf16x8 aC[M], aN[M], b0[NT], b1[NT];
#pragma unroll
  for (int m = 0; m < M; ++m) {
    aC[m] = *(const bf16x8*)(ab + ao[m] + ((16 * q) ^ sw[m]));
    aN[m] = *(const bf16x8*)(ab + ao[m] + ((64 + 16 * q) ^ sw[m]));
  }
#pragma unroll
  for (int t = 0; t < NT; ++t) b0[t] = ld8(br[t]);
#pragma unroll
  for (int t = 0; t < NT; ++t) b1[t] = ld8(br[t] + 32);
#pragma unroll
  for (int ks = 0; ks < KS - 2; ++ks) {
    bf16x8 aF[M], bF[NT];
    const int kb = 64 * (ks + 2) + 16 * q;
#pragma unroll
    for (int m = 0; m < M; ++m) aF[m] = *(const bf16x8*)(ab + ao[m] + (kb ^ sw[m]));
#pragma unroll
    for (int t = 0; t < NT; ++t) bF[t] = ld8(br[t] + (ks + 2) * 32);
#pragma unroll
    for (int t = 0; t < NT; ++t)
#pragma unroll
      for (int m = 0; m < M; ++m)
        acc[m][t] = MFMA16(aC[m], b0[t], acc[m][t], 0, 0, 0);
#pragma unroll
    for (int m = 0; m < M; ++m) { aC[m] = aN[m]; aN[m] = aF[m]; }
#pragma unroll
    for (int t = 0; t < NT; ++t) { b0[t] = b1[t]; b1[t] = bF[t]; }
  }
#pragma unroll
  for (int t = 0; t < NT; ++t)
#pragma unroll
    for (int m = 0; m < M; ++m) acc[m][t] = MFMA16(aC[m], b0[t], acc[m][t], 0, 0, 0);
#pragma unroll
  for (int t = 0; t < NT; ++t)
#pragma unroll
    for (int m = 0; m < M; ++m) acc[m][t] = MFMA16(aN[m], b1[t], acc[m][t], 0, 0, 0);
}

// ------- sweepT2: A (output h-rows) from global Wr2 rows, B = 2x16 enc rows from LDS ------
template<int NT, int KS>
__device__ __forceinline__ void sweepT2(const us* __restrict__ es, int q, int lo,
    const us* __restrict__ Ag, int n0, f32x4 (&acc)[2][NT]) {
  const char* eb = (const char*)es;
  int bo[2] = { lo * 640, (lo + 16) * 640 };
  int sb[2] = { swz(lo), swz(lo + 16) };
  const us* ar[NT];
#pragma unroll
  for (int t = 0; t < NT; ++t)
    ar[t] = Ag + (long)((n0 + t) * 16 + lo) * 320 + 8 * q;
  bf16x8 a0[NT], a1[NT], bC[2], bN[2];
#pragma unroll
  for (int t = 0; t < NT; ++t) a0[t] = ld8(ar[t]);
#pragma unroll
  for (int h = 0; h < 2; ++h)
    bC[h] = *(const bf16x8*)(eb + bo[h] + ((16 * q) ^ sb[h]));
#pragma unroll
  for (int t = 0; t < NT; ++t) a1[t] = ld8(ar[t] + 32);
#pragma unroll
  for (int h = 0; h < 2; ++h)
    bN[h] = *(const bf16x8*)(eb + bo[h] + ((64 + 16 * q) ^ sb[h]));
#pragma unroll
  for (int ks = 0; ks < KS - 2; ++ks) {
    bf16x8 a2[NT], bF[2];
    const int kb = 64 * (ks + 2) + 16 * q;
#pragma unroll
    for (int t = 0; t < NT; ++t) a2[t] = ld8(ar[t] + (ks + 2) * 32);
#pragma unroll
    for (int h = 0; h < 2; ++h)
      bF[h] = *(const bf16x8*)(eb + bo[h] + (kb ^ sb[h]));
#pragma unroll
    for (int t = 0; t < NT; ++t) {
      acc[0][t] = MFMA16(a0[t], bC[0], acc[0][t], 0, 0, 0);
      acc[1][t] = MFMA16(a0[t], bC[1], acc[1][t], 0, 0, 0);
    }
#pragma unroll
    for (int t = 0; t < NT; ++t) { a0[t] = a1[t]; a1[t] = a2[t]; }
#pragma unroll
    for (int h = 0; h < 2; ++h) { bC[h] = bN[h]; bN[h] = bF[h]; }
  }
#pragma unroll
  for (int t = 0; t < NT; ++t) {
    acc[0][t] = MFMA16(a0[t], bC[0], acc[0][t], 0, 0, 0);
    acc[1][t] = MFMA16(a0[t], bC[1], acc[1][t], 0, 0, 0);
  }
#pragma unroll
  for (int t = 0; t < NT; ++t) {
    acc[0][t] = MFMA16(a1[t], bN[0], acc[0][t], 0, 0, 0);
    acc[1][t] = MFMA16(a1[t], bN[1], acc[1][t], 0, 0, 0);
  }
}

// ------- sweepG: both operands from global (depth-2) — for k_doc logits ----------
template<int NT>
__device__ __forceinline__ void sweepG(const us* __restrict__ Ab,
    const us* __restrict__ Bb, int m0, int nt0, int lo, int q, int ksn, f32x4* acc) {
  const us* ar = Ab + (long)(m0 + lo) * 320 + 8 * q;
  const us* br[NT];
#pragma unroll
  for (int t = 0; t < NT; ++t)
    br[t] = Bb + (long)((nt0 + t) * 16 + lo) * 320 + 8 * q;
  bf16x8 a0 = ld8(ar), a1 = ld8(ar + 32);
  bf16x8 b0[NT], b1[NT];
#pragma unroll
  for (int t = 0; t < NT; ++t) b0[t] = ld8(br[t]);
#pragma unroll
  for (int t = 0; t < NT; ++t) b1[t] = ld8(br[t] + 32);
  for (int ks = 0; ks < ksn - 2; ++ks) {
    bf16x8 a2 = ld8(ar + (ks + 2) * 32);
    bf16x8 b2[NT];
#pragma unroll
    for (int t = 0; t < NT; ++t) b2[t] = ld8(br[t] + (ks + 2) * 32);
#pragma unroll
    for (int t = 0; t < NT; ++t)
      acc[t] = MFMA16(a0, b0[t], acc[t], 0, 0, 0);
    a0 = a1; a1 = a2;
#pragma unroll
    for (int t = 0; t < NT; ++t) { b0[t] = b1[t]; b1[t] = b2[t]; }
  }
#pragma unroll
  for (int t = 0; t < NT; ++t)
    acc[t] = MFMA16(a0, b0[t], acc[t], 0, 0, 0);
#pragma unroll
  for (int t = 0; t < NT; ++t)
    acc[t] = MFMA16(a1, b1[t], acc[t], 0, 0, 0);
}

// ------- K1: y==0: gather + enc + scores (256 blocks); y==1: convert Wp/Wc/Wr3/c2 ---------
__global__ __launch_bounds__(256) void k_encprep(
    const int* __restrict__ wi, const float* __restrict__ E,
    const us* __restrict__ Wsb, const float* __restrict__ b_sent,
    const float* __restrict__ w_root,
    const float* __restrict__ Wp, const float* __restrict__ Wc,
    const float* __restrict__ Wr, const float* __restrict__ root,
    us* __restrict__ encG, float* __restrict__ scG,
    us* __restrict__ Wpb, us* __restrict__ Wcb, us* __restrict__ Wr3b,
    float* __restrict__ c2) {
  int t = threadIdx.x;
  if (blockIdx.y == 1) {
    // weight conversions (independent of enc): Wp, Wc, Wr3 panels, c2
    int gid = blockIdx.x * 256 + t;
    const int stride = 256 * 256;
    for (int i = gid; i < 5 * 102400; i += stride) {
      int p = i / 102400, rem = i - p * 102400;
      int r = rem / 320, c = rem - r * 320;
      us v = 0;
      if (r < 300 && c < 300) {
        if (p == 0)      v = f2b(Wp[r * 300 + c]);
        else if (p == 1) v = f2b(Wc[r * 300 + c]);
        else             v = f2b(Wr[r * 900 + (p - 2) * 300 + c]);
      }
      if (p == 0)      Wpb[rem] = v;
      else if (p == 1) Wcb[rem] = v;
      else             Wr3b[(p - 2) * 102400 + rem] = v;
    }
    if (gid < 2560) {   // c2[c] = sum_h Wr2[c][h]*root[h]
      int c = gid >> 3, p = gid & 7;
      float s = 0.f;
      if (c < 300)
        for (int h = p; h < 300; h += 8) s = fmaf(Wr[c * 900 + 300 + h], root[h], s);
      s += __shfl_xor(s, 1); s += __shfl_xor(s, 2); s += __shfl_xor(s, 4);
      if (p == 0) c2[c] = s;
    }
    return;
  }
  // ---- y==0: enc path ----
  __shared__ __align__(16) us xs[16 * 320];
  __shared__ __align__(16) us es[16 * 320];
  int r0g = blockIdx.x * 16;
  {
    int row = t >> 4, p = t & 15;
    int widx = wi[((r0g + row) << 6) + 63];
    const float4* er = (const float4*)(E + (long)widx * 300);
    char* rowb = (char*)xs + row * 640;
    int sw = swz(row);
    for (int j = p; j < 75; j += 16) {
      float4 v = er[j];
      *(ushort4*)(rowb + ((8 * j) ^ sw)) =
          make_ushort4(f2b(v.x), f2b(v.y), f2b(v.z), f2b(v.w));
    }
    for (int c = 300 + p; c < 320; c += 16)    // zero K-pad cols
      *(us*)(rowb + ((2 * c) ^ sw)) = 0;
  }
  __syncthreads();
  int w = t >> 6, lane = t & 63, lo = lane & 15, q = lane >> 4;
  const f32x4 z4 = {0.f, 0.f, 0.f, 0.f};
  int rr[1] = { lo };
  f32x4 acc[1][5];
#pragma unroll
  for (int b = 0; b < 5; ++b) acc[0][b] = z4;
  sweepM<1, 5, 10>(xs, rr, q, lo, Wsb, w * 5, acc);
#pragma unroll
  for (int tt = 0; tt < 5; ++tt) {
    int col = (w * 5 + tt) * 16 + lo;
    float bb = (col < 300) ? b_sent[col] : 0.f;
#pragma unroll
    for (int r = 0; r < 4; ++r) {
      int row = 4 * q + r;
      us hv = (col < 300) ? f2b(lrelu(acc[0][tt][r] + bb)) : (us)0;
      *(us*)((char*)es + row * 640 + ((2 * col) ^ swz(row))) = hv;
      encG[(long)(r0g + row) * 320 + col] = hv;
    }
  }
  __syncthreads();
  // scores = enc @ w_root (b_root omitted: softmax-invariant)
  {
    int row = t >> 4, p = t & 15;
    float s = 0.f;
    for (int cch = p; cch < 38; cch += 16) {
      bf16x8 v = *(const bf16x8*)((const char*)es + row * 640 + ((16 * cch) ^ swz(row)));
#pragma unroll
      for (int e = 0; e < 8; ++e) {
        int h = cch * 8 + e;
        if (h < 300) s = fmaf(b2f((us)v[e]), w_root[h], s);
      }
    }
    s += __shfl_xor(s, 1); s += __shfl_xor(s, 2); s += __shfl_xor(s, 4); s += __shfl_xor(s, 8);
    if (p == 0) scG[r0g + row] = s;
  }
}

// ---------------- K2: 128 row-tiles (32 rows) x 5 tasks {P, C, G1, G3, G2eT} --------------
__global__ __launch_bounds__(256) void k_panels(
    const us* __restrict__ encG,
    const us* __restrict__ Wpb, const us* __restrict__ Wcb, const us* __restrict__ Wrb,
    const float* __restrict__ b_par, const float* __restrict__ b_ch,
    us* __restrict__ Pg, us* __restrict__ Cg, us* __restrict__ G1g, us* __restrict__ G3g,
    us* __restrict__ G2eT) {
  __shared__ __align__(16) us es[32 * 320];
  int t = threadIdx.x, task = blockIdx.y, rt = blockIdx.x;
  // stage 32-row enc tile (pad cols already zero in encG), swizzled
  {
    const float4* src = (const float4*)(encG + (long)rt * 32 * 320);
    for (int i = t; i < 1280; i += 256) {
      int row = i / 40, c16 = i - row * 40;
      float4 v = src[i];
      *(float4*)((char*)es + row * 640 + ((c16 * 16) ^ swz(row))) = v;
    }
  }
  __syncthreads();
  int w = t >> 6, lane = t & 63, lo = lane & 15, q = lane >> 4;
  const f32x4 z4 = {0.f, 0.f, 0.f, 0.f};
  if (task == 4) {
    // G2eT[h][row] = (enc @ Wr2^T)^T : A = Wr2 rows (h, global), B = 2x16 enc rows (LDS)
    f32x4 acc[2][5];
#pragma unroll
    for (int a = 0; a < 2; ++a)
#pragma unroll
      for (int b = 0; b < 5; ++b) acc[a][b] = z4;
    sweepT2<5, 10>(es, q, lo, Wrb + 102400, w * 5, acc);
#pragma unroll
    for (int half = 0; half < 2; ++half)
#pragma unroll
      for (int tt = 0; tt < 5; ++tt)
#pragma unroll
        for (int r = 0; r < 4; ++r) {
          int h = (w * 5 + tt) * 16 + 4 * q + r;
          G2eT[(long)h * 4096 + rt * 32 + half * 16 + lo] =
              (h < 300) ? f2b(acc[half][tt][r]) : (us)0;
        }
  } else {
    const us* Bg = (task == 0) ? Wpb : (task == 1) ? Wcb : (task == 2) ? Wrb : Wrb + 204800;
    int rr[2] = { lo, 16 + lo };
    f32x4 acc[2][5];
#pragma unroll
    for (int a = 0; a < 2; ++a)
#pragma unroll
      for (int b = 0; b < 5; ++b) acc[a][b] = z4;
    sweepM<2, 5, 10>(es, rr, q, lo, Bg, w * 5, acc);
    if (task < 2) {
      const float* bias = (task == 0) ? b_par : b_ch;
      us* outb = (task == 0) ? Pg : Cg;
#pragma unroll
      for (int m = 0; m < 2; ++m)
#pragma unroll
        for (int tt = 0; tt < 5; ++tt) {
          int col = (w * 5 + tt) * 16 + lo;
          float bb = (col < 300) ? bias[col] : 0.f;
#pragma unroll
          for (int r = 0; r < 4; ++r) {
            int row = rt * 32 + m * 16 + 4 * q + r;
            outb[(long)row * 320 + col] =
                (col < 300) ? f2b(lrelu(acc[m][tt][r] + bb)) : (us)0;
          }
        }
    } else {
      us* outb = (task == 2) ? G1g : G3g;
#pragma unroll
      for (int m = 0; m < 2; ++m)
#pragma unroll
        for (int tt = 0; tt < 5; ++tt) {
          int col = (w * 5 + tt) * 16 + lo;
          if (col < 300)
#pragma unroll
            for (int r = 0; r < 4; ++r)
              outb[(long)(rt * 32 + m * 16 + 4 * q + r) * 320 + col] = f2b(acc[m][tt][r]);
        }
    }
  }
}

// ---------------- K3: per-doc logits, softmax, A/fri out, G2r, combine, out ----------------
__global__ __launch_bounds__(512) void k_doc(
    const us* __restrict__ Pg, const us* __restrict__ Cg, const us* __restrict__ G2eT,
    const us* __restrict__ G1g, const us* __restrict__ G3g,
    const float* __restrict__ scG, const float* __restrict__ c2,
    const float* __restrict__ b_r, const float* __restrict__ W_cls,
    const float* __restrict__ b_cls,
    float* __restrict__ outp, float* __restrict__ outA, float* __restrict__ outF) {
  __shared__ __align__(16) float LA[64 * 68];
  __shared__ __align__(16) us AtL[64 * 72];
  __shared__ float pm[512], ps[512];
  __shared__ float friS[64], rsS[64];
  __shared__ float finP2[4 * 320];
  int d = blockIdx.x, t = threadIdx.x;
  int w = t >> 6, lane = t & 63, lo = lane & 15, q = lane >> 4;
  const f32x4 z4 = {0.f, 0.f, 0.f, 0.f};

  if (t < 64) {    // fri = softmax(scores)
    float sc = scG[d * 64 + t], m = sc;
#pragma unroll
    for (int o = 32; o > 0; o >>= 1) m = fmaxf(m, __shfl_xor(m, o));
    float e = expf(sc - m), sum = e;
#pragma unroll
    for (int o = 32; o > 0; o >>= 1) sum += __shfl_xor(sum, o);
    float f = e / sum;
    friS[t] = f;
    outF[d * 64 + t] = f;
  }

  // logits L = P @ C^T (64x64, K=320)
  {
    const us* Pd = Pg + (long)d * 64 * 320;
    const us* Cd = Cg + (long)d * 64 * 320;
    int m = w >> 1, np = (w & 1) * 2;
    f32x4 acc2[2] = { z4, z4 };
    sweepG<2>(Pd, Cd, m * 16, np, lo, q, 10, acc2);
#pragma unroll
    for (int r = 0; r < 4; ++r) {
      int row = m * 16 + 4 * q + r;
      int c0 = np * 16 + lo, c1 = c0 + 16;
      LA[row * 68 + c0] = (row == c0) ? NEG_INF : acc2[0][r];
      LA[row * 68 + c1] = (row == c1) ? NEG_INF : acc2[1][r];
    }
  }
  __syncthreads();

  // column softmax over i for each j; write A (fp32), AtL (bf16), LA=a
  {
    int j = lane;
    float mx = -3.0e38f;
#pragma unroll
    for (int ii = 0; ii < 8; ++ii) mx = fmaxf(mx, LA[(w * 8 + ii) * 68 + j]);
    pm[w * 64 + j] = mx;
    __syncthreads();
    float gm = pm[j];
#pragma unroll
    for (int k = 1; k < 8; ++k) gm = fmaxf(gm, pm[k * 64 + j]);
    float ev[8], ss = 0.f;
#pragma unroll
    for (int ii = 0; ii < 8; ++ii) {
      float e = expf(LA[(w * 8 + ii) * 68 + j] - gm);
      ev[ii] = e; ss += e;
    }
    ps[w * 64 + j] = ss;
    __syncthreads();
    float tot = ps[j];
#pragma unroll
    for (int k = 1; k < 8; ++k) tot += ps[k * 64 + j];
    float inv = 1.f / tot;
    float* Ad = outA + (long)d * 4096;
#pragma unroll
    for (int ii = 0; ii < 8; ++ii) {
      int i = w * 8 + ii;
      float a = ev[ii] * inv;
      Ad[i * 64 + j] = a;
      AtL[j * 72 + i] = f2b(a);
      LA[i * 68 + j] = a;
    }
  }
  __syncthreads();
  if (t < 64) {   // rs[i] = sum_j A[i][j]
    float s = 0.f;
    for (int jj = 0; jj < 64; ++jj) s += LA[t * 68 + jj];
    rsS[t] = s;
  }
  __syncthreads();

  // G2r = A^T @ G2e (K=64) + combine + column-reduce over sentences
  {
    int mg = w & 3, nh = w >> 2;
    f32x4 a10[10];
#pragma unroll
    for (int b = 0; b < 10; ++b) a10[b] = z4;
#pragma unroll
    for (int ks = 0; ks < 2; ++ks) {
      bf16x8 aA = ld8(AtL + (mg * 16 + lo) * 72 + 32 * ks + 8 * q);
#pragma unroll
      for (int tt = 0; tt < 10; ++tt) {
        bf16x8 bv = ld8(G2eT + (long)((nh * 10 + tt) * 16 + lo) * 4096 +
                        d * 64 + 32 * ks + 8 * q);
        a10[tt] = MFMA16(aA, bv, a10[tt], 0, 0, 0);
      }
    }
#pragma unroll
    for (int tt = 0; tt < 10; ++tt) {
      int col = (nh * 10 + tt) * 16 + lo;
      if (col < 300) {
        float bb = b_r[col], cc = c2[col];
        float csum = 0.f;
#pragma unroll
        for (int r = 0; r < 4; ++r) {
          int i = mg * 16 + 4 * q + r;
          float g1 = b2f(G1g[(long)(d * 64 + i) * 320 + col]);
          float g3 = b2f(G3g[(long)(d * 64 + i) * 320 + col]);
          csum += lrelu(a10[tt][r] + g1 + rsS[i] * g3 + friS[i] * cc + bb);
        }
        csum += __shfl_xor(csum, 16);
        csum += __shfl_xor(csum, 32);
        if (q == 0) finP2[mg * 320 + col] = csum;
      }
    }
  }
  __syncthreads();

  if (t < 128) {   // out = (mean_i ri) @ W_cls^T + b_cls
    int cls = t >> 6, ln = t & 63;
    float s = 0.f;
    for (int h = ln; h < 300; h += 64)
      s += (finP2[h] + finP2[320 + h] + finP2[640 + h] + finP2[960 + h]) *
           W_cls[cls * 300 + h];
#pragma unroll
    for (int o = 32; o > 0; o >>= 1) s += __shfl_xor(s, o);
    if (ln == 0) outp[d * 2 + cls] = s * 0.015625f + b_cls[cls];
  }
}

extern "C" void kernel_launch(void* const* d_in, const int* in_sizes, int n_in,
                              void* d_out, int out_size, void* d_ws, size_t ws_size,
                              hipStream_t stream) {
  const int*   wi     = (const int*)d_in[0];
  const float* E      = (const float*)d_in[1];
  const float* W_sent = (const float*)d_in[2];
  const float* b_sent = (const float*)d_in[3];
  const float* W_par  = (const float*)d_in[4];
  const float* b_par  = (const float*)d_in[5];
  const float* W_ch   = (const float*)d_in[6];
  const float* b_ch   = (const float*)d_in[7];
  const float* w_root = (const float*)d_in[8];
  const float* b_root = (const float*)d_in[9];  (void)b_root;
  const float* root_e = (const float*)d_in[10];
  const float* W_r    = (const float*)d_in[11];
  const float* b_r    = (const float*)d_in[12];
  const float* W_cls  = (const float*)d_in[13];
  const float* b_cls  = (const float*)d_in[14];

  us* B = (us*)d_ws;
  us* Wsb   = B;                      // [320][320] bf16
  us* Wpb   = B + 102400;
  us* Wcb   = B + 204800;
  us* Wr3b  = B + 307200;             // 3 x [320][320] bf16
  float* c2 = (float*)(B + 614400);   // [320] fp32
  us* encG  = B + 615040;             // [4096][320] bf16
  us* Pg    = B + 1925760;
  us* Cg    = B + 3236480;
  us* G1g   = B + 4547200;
  us* G3g   = B + 5857920;
  us* G2eT  = B + 7168640;            // [320][4096] bf16 (transposed G2e)
  float* scG = (float*)(B + 8479360); // [4096] fp32 scores

  float* outp = (float*)d_out;        // [out(128) | A(262144) | fri(4096)]
  float* outA = outp + 128;
  float* outF = outp + 128 + 262144;

  k_prep0<<<128, 256, 0, stream>>>(W_sent, Wsb);
  k_encprep<<<dim3(256, 2), 256, 0, stream>>>(wi, E, Wsb, b_sent, w_root,
                                              W_par, W_ch, W_r, root_e,
                                              encG, scG, Wpb, Wcb, Wr3b, c2);
  k_panels<<<dim3(128, 5), 256, 0, stream>>>(encG, Wpb, Wcb, Wr3b,
                                             b_par, b_ch, Pg, Cg, G1g, G3g, G2eT);
  k_doc<<<64, 512, 0, stream>>>(Pg, Cg, G2eT, G1g, G3g, scG, c2,
                                b_r, W_cls, b_cls, outp, outA, outF);
}